// Round 18
// baseline (220.937 us; speedup 1.0000x reference)
//
#include <hip/hip_runtime.h>
#include <hip/hip_fp16.h>

#define N_NODES 100000
#define N_EDGES 1600000
#define DIM 64
#define NEG_SLOPE 0.2f
#define CAP 64
#define NB 256          // partition bins == chunks
#define BW 391          // bin width: 256*391 = 100096 >= N
#define PACKB 512

__device__ __forceinline__ float elu_f(float v) {
    return v > 0.f ? v : (__expf(v) - 1.f);
}
__device__ __forceinline__ float leaky_f(float v) {
    return v > 0.f ? v : NEG_SLOPE * v;
}
__device__ __forceinline__ int pad4(int v) { return (v + 3) & ~3; }

__device__ __forceinline__ unsigned int pkh2(float a, float b) {
    __half2 h = __floats2half2_rn(a, b);
    return *(unsigned int*)&h;
}
__device__ __forceinline__ float2 uph2(unsigned int u) {
    __half2 h = *(__half2*)&u;
    return __half22float2(h);
}

typedef _Float16 f16x8 __attribute__((ext_vector_type(8)));
typedef float f32x4 __attribute__((ext_vector_type(4)));

__device__ __forceinline__ f16x8 u4_to_f16x8(uint4 u) {
    f16x8 r;
    __builtin_memcpy(&r, &u, 16);
    return r;
}

__device__ __forceinline__ int chunk_beg4(int c, int E4) {
    return (int)(((long long)c * E4) / NB);
}

// ---- K1: hist (blocks 0..NB-1): per-chunk 256-bin LDS histogram of dst
//      (int4). Pack (blocks NB..): x->half2 (float4, 16 lanes/node) + alphas
//      + wpk + dummy node. ----
__global__ void __launch_bounds__(256) k_hist(
    const int4* __restrict__ dst4, int* __restrict__ blockHist,
    const float4* __restrict__ xf4, const float* __restrict__ Wgcn,
    const float* __restrict__ Wss, const float* __restrict__ Wsn,
    const float* __restrict__ Wgin, const float* __restrict__ Wgat,
    const float* __restrict__ a_src, const float* __restrict__ a_dst,
    unsigned int* __restrict__ xh, float2* __restrict__ scal2,
    float* __restrict__ alpha_d, unsigned int* __restrict__ wpk, int E4,
    int N) {
    if ((int)blockIdx.x < NB) {
        __shared__ int hist[NB];
        for (int j = threadIdx.x; j < NB; j += 256) hist[j] = 0;
        __syncthreads();
        const int beg = chunk_beg4(blockIdx.x, E4);
        const int end = chunk_beg4(blockIdx.x + 1, E4);
        for (int i = beg + threadIdx.x; i < end; i += 256) {
            int4 d = dst4[i];
            atomicAdd(&hist[d.x / BW], 1);
            atomicAdd(&hist[d.y / BW], 1);
            atomicAdd(&hist[d.z / BW], 1);
            atomicAdd(&hist[d.w / BW], 1);
        }
        __syncthreads();
        for (int j = threadIdx.x; j < NB; j += 256)
            blockHist[j * NB + blockIdx.x] = hist[j];  // bin-major
        return;
    }

    const int pbid = blockIdx.x - NB;
    __shared__ float svs[64], svd[64];
    if (threadIdx.x < 64) {
        int t = threadIdx.x;
        float vs = 0.f, vd = 0.f;
        for (int j = 0; j < 64; j++) {
            float w = Wgat[t * 64 + j];
            vs = fmaf(w, a_src[j], vs);
            vd = fmaf(w, a_dst[j], vd);
        }
        svs[t] = vs;
        svd[t] = vd;
    }
    __syncthreads();

    if (pbid == 0) {
        if (threadIdx.x < 32) xh[(size_t)N * 32 + threadIdx.x] = 0u;
        if (threadIdx.x == 32) scal2[N] = make_float2(-1e30f, 0.f);
    }
    if (pbid == 1) {
        // wpk[idx], idx = (((m*2+ks)*4+ct)*64+lane)*4+jp  (MFMA B-frag layout)
        for (int idx = threadIdx.x; idx < 10240; idx += 256) {
            int jp = idx & 3;
            int lane = (idx >> 2) & 63;
            int ct = (idx >> 8) & 3;
            int mks = idx >> 10;
            int m = mks >> 1, ks = mks & 1;
            int k = ks * 32 + ((lane >> 4) << 3) + jp * 2;
            int col = ct * 16 + (lane & 15);
            const float* Wm = (m == 0)   ? Wgcn
                              : (m == 1) ? Wss
                              : (m == 2) ? Wsn
                              : (m == 3) ? Wgin
                                         : Wgat;
            wpk[idx] = pkh2(Wm[k * 64 + col], Wm[(k + 1) * 64 + col]);
        }
    }

    const int lane = threadIdx.x & 63;
    const int wv = threadIdx.x >> 6;
    const int c16 = lane & 15;
    const int g4 = lane >> 4;  // node-in-quad
    const int nquads = N / 4;

    for (int q = pbid * 4 + wv; q < nquads; q += PACKB * 4) {
        int n = q * 4 + g4;
        float4 x4 = xf4[(size_t)n * 16 + c16];
        uint2 pk = make_uint2(pkh2(x4.x, x4.y), pkh2(x4.z, x4.w));
        ((uint2*)xh)[(size_t)n * 16 + c16] = pk;
        float ps = x4.x * svs[4 * c16] + x4.y * svs[4 * c16 + 1] +
                   x4.z * svs[4 * c16 + 2] + x4.w * svs[4 * c16 + 3];
        float pd = x4.x * svd[4 * c16] + x4.y * svd[4 * c16 + 1] +
                   x4.z * svd[4 * c16 + 2] + x4.w * svd[4 * c16 + 3];
#pragma unroll
        for (int m = 8; m; m >>= 1) {
            ps += __shfl_xor(ps, m, 64);
            pd += __shfl_xor(pd, m, 64);
        }
        if (c16 == 0) {
            scal2[n].x = ps;
            alpha_d[n] = pd;
        }
    }
}

// ---- K2: partition with self-computed offsets; packed (src | rem<<17).
//      1024 threads: 16 waves/CU to hide scattered-store latency. ----
__global__ void __launch_bounds__(1024) k_part(const int4* __restrict__ src4,
                                               const int4* __restrict__ dst4,
                                               const int* __restrict__ bh,
                                               int* __restrict__ esrtP,
                                               int* __restrict__ binBase,
                                               int E4, int E) {
    __shared__ int off[NB];
    __shared__ int tmp[NB];
    const int t = threadIdx.x;
    const int chunk = blockIdx.x;

    // per-bin total + prefix up to my chunk (thread t<NB owns bin t)
    int myTot = 0, myPre = 0;
    if (t < NB) {
        const int* row = bh + t * NB;
        for (int i = 0; i < NB; i++) {
            int v = row[i];
            myTot += v;
            if (i < chunk) myPre += v;
        }
        tmp[t] = myTot;
    }
    __syncthreads();
    for (int d = 1; d < NB; d <<= 1) {
        int v = (t >= d && t < NB) ? tmp[t - d] : 0;
        __syncthreads();
        if (t < NB) tmp[t] += v;
        __syncthreads();
    }
    if (t < NB) {
        int binExcl = tmp[t] - myTot;
        off[t] = binExcl + myPre;
        if (chunk == 0) {
            binBase[t] = binExcl;
            if (t == 0) binBase[NB] = E;
        }
    }
    __syncthreads();

    const int beg = chunk_beg4(chunk, E4);
    const int end = chunk_beg4(chunk + 1, E4);
    for (int i = beg + t; i < end; i += 1024) {
        int4 s = src4[i];
        int4 d = dst4[i];
        int b0 = d.x / BW, b1 = d.y / BW, b2 = d.z / BW, b3 = d.w / BW;
        int p0 = atomicAdd(&off[b0], 1);
        esrtP[p0] = s.x | ((d.x - b0 * BW) << 17);
        int p1 = atomicAdd(&off[b1], 1);
        esrtP[p1] = s.y | ((d.y - b1 * BW) << 17);
        int p2 = atomicAdd(&off[b2], 1);
        esrtP[p2] = s.z | ((d.z - b2 * BW) << 17);
        int p3 = atomicAdd(&off[b3], 1);
        esrtP[p3] = s.w | ((d.w - b3 * BW) << 17);
    }
}

// ---- K3: per-bin fill (1024 threads): LDS slot counters -> srtF + ncnt + dinv ----
__global__ void __launch_bounds__(1024) k_fill2(const int* __restrict__ esrtP,
                                                const int* __restrict__ binBase,
                                                int* __restrict__ srtF,
                                                int* __restrict__ ncnt,
                                                float2* __restrict__ scal2,
                                                int N) {
    __shared__ int lcnt[BW];
    const int j = blockIdx.x;
    const int lo = j * BW;
    for (int k = threadIdx.x; k < BW; k += 1024) lcnt[k] = 0;
    __syncthreads();
    const int beg = binBase[j];
    const int end = binBase[j + 1];
    for (int i = beg + threadIdx.x; i < end; i += 1024) {
        int v = esrtP[i];
        int s = v & 131071;
        int rem = v >> 17;
        int sl = atomicAdd(&lcnt[rem], 1);
        if (sl < CAP) srtF[(size_t)(lo + rem) * CAP + sl] = s;
    }
    __syncthreads();
    for (int k = threadIdx.x; k < BW; k += 1024) {
        int n = lo + k;
        if (n < N) {
            int cv = lcnt[k];
            ncnt[n] = cv;
            scal2[n].y = rsqrtf((float)(cv + 1));
        }
    }
}

// ---- K4: fused aggregation + MFMA finalize. Block (8 waves) per 16-node
//      tile: each wave aggregates 2 nodes in parallel -> packed aggs to LDS
//      (97-stride), barrier, wave 0 runs the 5-GEMV MFMA finalize for the
//      tile (weights from L2-hot wpk). No global agg round-trip. ----
__global__ void __launch_bounds__(512) k_aggfin(
    const unsigned int* __restrict__ xh, const float2* __restrict__ scal2,
    const float* __restrict__ alpha_d, const int* __restrict__ ncnt,
    const int* __restrict__ srtF, const uint4* __restrict__ xh4,
    const uint4* __restrict__ wpk4, const float* __restrict__ wts,
    float* __restrict__ out, int NT) {
    __shared__ int sSl[8][64];
    __shared__ float2 sED[8][64];
    __shared__ unsigned int sAgg[16][97];  // 97-stride: conflict-free nl reads
    __shared__ float sDen[16];

    const int lane = threadIdx.x & 63;
    const int w = threadIdx.x >> 6;  // 0..7
    const int c = lane & 31;
    const int hf = lane >> 5;
    const int kg = lane >> 4;  // finalize k-group
    const int nl = lane & 15;  // finalize node-in-tile
    const float w0 = wts[0], w1 = wts[1], w2 = wts[2], w3 = wts[3];

    for (int t = blockIdx.x; t < NT; t += gridDim.x) {
#pragma unroll
        for (int rep = 0; rep < 2; rep++) {
            const int row = rep * 8 + w;
            const int n = t * 16 + row;
            const int deg = min(ncnt[n], CAP);
            const float ad = alpha_d[n];

            int sl = (lane < deg) ? srtF[(size_t)n * CAP + lane] : N_NODES;
            float2 sc = scal2[sl];
            float ee = __expf(leaky_f(sc.x + ad));  // dummy: exp(-inf)=0
            float den = ee;
            sSl[w][lane] = sl;
            sED[w][lane] = make_float2(ee, sc.y);

            float2 an = {0.f, 0.f}, ag = {0.f, 0.f}, aa = {0.f, 0.f};
            const int jmax = pad4(deg);
            int j = 0;
            for (; j + 16 <= jmax; j += 16) {
                int ss[8];
                float2 ed[8];
                unsigned int uu[8];
#pragma unroll
                for (int k = 0; k < 8; k++) {
                    int b = j + hf + 2 * k;
                    ss[k] = sSl[w][b];
                    ed[k] = sED[w][b];
                }
#pragma unroll
                for (int k = 0; k < 8; k++) uu[k] = xh[(size_t)ss[k] * 32 + c];
#pragma unroll
                for (int k = 0; k < 8; k++) {
                    float2 f = uph2(uu[k]);
                    an.x += f.x;
                    an.y += f.y;
                    ag.x = fmaf(ed[k].y, f.x, ag.x);
                    ag.y = fmaf(ed[k].y, f.y, ag.y);
                    aa.x = fmaf(ed[k].x, f.x, aa.x);
                    aa.y = fmaf(ed[k].x, f.y, aa.y);
                }
            }
            if (j + 8 <= jmax) {
                int b0 = j + hf, b1 = b0 + 2, b2 = b0 + 4, b3 = b0 + 6;
                int s0 = sSl[w][b0], s1 = sSl[w][b1];
                int s2 = sSl[w][b2], s3 = sSl[w][b3];
                float2 e0 = sED[w][b0], e1 = sED[w][b1];
                float2 e2 = sED[w][b2], e3 = sED[w][b3];
                unsigned int u0 = xh[(size_t)s0 * 32 + c];
                unsigned int u1 = xh[(size_t)s1 * 32 + c];
                unsigned int u2 = xh[(size_t)s2 * 32 + c];
                unsigned int u3 = xh[(size_t)s3 * 32 + c];
                float2 f0 = uph2(u0), f1 = uph2(u1);
                float2 f2 = uph2(u2), f3 = uph2(u3);
                an.x += (f0.x + f1.x) + (f2.x + f3.x);
                an.y += (f0.y + f1.y) + (f2.y + f3.y);
                ag.x = fmaf(e0.y, f0.x,
                            fmaf(e1.y, f1.x,
                                 fmaf(e2.y, f2.x, fmaf(e3.y, f3.x, ag.x))));
                ag.y = fmaf(e0.y, f0.y,
                            fmaf(e1.y, f1.y,
                                 fmaf(e2.y, f2.y, fmaf(e3.y, f3.y, ag.y))));
                aa.x = fmaf(e0.x, f0.x,
                            fmaf(e1.x, f1.x,
                                 fmaf(e2.x, f2.x, fmaf(e3.x, f3.x, aa.x))));
                aa.y = fmaf(e0.x, f0.y,
                            fmaf(e1.x, f1.y,
                                 fmaf(e2.x, f2.y, fmaf(e3.x, f3.y, aa.y))));
                j += 8;
            }
            if (j < jmax) {
                int b0 = j + hf, b1 = b0 + 2;
                int s0 = sSl[w][b0], s1 = sSl[w][b1];
                float2 e0 = sED[w][b0], e1 = sED[w][b1];
                unsigned int u0 = xh[(size_t)s0 * 32 + c];
                unsigned int u1 = xh[(size_t)s1 * 32 + c];
                float2 f0 = uph2(u0), f1 = uph2(u1);
                an.x += f0.x + f1.x;
                an.y += f0.y + f1.y;
                ag.x = fmaf(e0.y, f0.x, fmaf(e1.y, f1.x, ag.x));
                ag.y = fmaf(e0.y, f0.y, fmaf(e1.y, f1.y, ag.y));
                aa.x = fmaf(e0.x, f0.x, fmaf(e1.x, f1.x, aa.x));
                aa.y = fmaf(e0.x, f0.y, fmaf(e1.x, f1.y, aa.y));
            }

            an.x += __shfl_xor(an.x, 32, 64);
            an.y += __shfl_xor(an.y, 32, 64);
            ag.x += __shfl_xor(ag.x, 32, 64);
            ag.y += __shfl_xor(ag.y, 32, 64);
            aa.x += __shfl_xor(aa.x, 32, 64);
            aa.y += __shfl_xor(aa.y, 32, 64);
#pragma unroll
            for (int m = 32; m; m >>= 1) den += __shfl_xor(den, m, 64);

            if (lane < 32) {
                sAgg[row][c] = pkh2(an.x, an.y);
                sAgg[row][32 + c] = pkh2(ag.x, ag.y);
                sAgg[row][64 + c] = pkh2(aa.x, aa.y);
            }
            if (lane == 0) sDen[row] = den;
        }
        __syncthreads();

        // ---- finalize phase: wave 0 only ----
        if (w == 0) {
            const int n = t * 16 + nl;
            const int cnt = ncnt[n];
            const float ad = alpha_d[n];
            const float2 scn = scal2[n];
            const float dv = scn.y;
            const float as = scn.x;
            const float den = sDen[nl];
            const float ee_s = __expf(leaky_f(as + ad));
            const float dent = den + ee_s;
            const float icnt = 1.f / fmaxf((float)cnt, 1.f);
            const float dv2 = dv * dv;

            unsigned int fa[5][2][4];
#pragma unroll
            for (int ks = 0; ks < 2; ks++) {
                uint4 uX = xh4[(size_t)n * 8 + ks * 4 + kg];
                unsigned int ux[4] = {uX.x, uX.y, uX.z, uX.w};
#pragma unroll
                for (int c4 = 0; c4 < 4; c4++) {
                    int pidx = ks * 16 + kg * 4 + c4;
                    float2 xf = uph2(ux[c4]);
                    float xx = xf.x, xy = xf.y;
                    float2 nn = uph2(sAgg[nl][pidx]);
                    float2 gg = uph2(sAgg[nl][32 + pidx]);
                    float2 av = uph2(sAgg[nl][64 + pidx]);
                    fa[0][ks][c4] = pkh2(fmaf(dv, gg.x, dv2 * xx),
                                         fmaf(dv, gg.y, dv2 * xy));  // GCN
                    fa[1][ks][c4] = ux[c4];                          // x
                    fa[2][ks][c4] = pkh2(nn.x * icnt, nn.y * icnt);  // nmean
                    fa[3][ks][c4] = pkh2(xx + nn.x, xy + nn.y);      // GIN
                    fa[4][ks][c4] = pkh2(fmaf(ee_s, xx, av.x) / dent,
                                         fmaf(ee_s, xy, av.y) / dent);  // GAT
                }
            }
            f16x8 A[5][2];
#pragma unroll
            for (int m = 0; m < 5; m++)
#pragma unroll
                for (int ks = 0; ks < 2; ks++) {
                    uint4 u = make_uint4(fa[m][ks][0], fa[m][ks][1],
                                         fa[m][ks][2], fa[m][ks][3]);
                    A[m][ks] = u4_to_f16x8(u);
                }

            float res[4][4];
            const f32x4 zero = {0.f, 0.f, 0.f, 0.f};
#pragma unroll
            for (int ct = 0; ct < 4; ct++) {
                f32x4 acc = __builtin_amdgcn_mfma_f32_16x16x32_f16(
                    A[0][0], u4_to_f16x8(wpk4[(0 * 4 + ct) * 64 + lane]), zero,
                    0, 0, 0);
                acc = __builtin_amdgcn_mfma_f32_16x16x32_f16(
                    A[0][1], u4_to_f16x8(wpk4[(1 * 4 + ct) * 64 + lane]), acc,
                    0, 0, 0);
#pragma unroll
                for (int r = 0; r < 4; r++) res[ct][r] = w0 * elu_f(acc[r]);
                acc = __builtin_amdgcn_mfma_f32_16x16x32_f16(
                    A[1][0], u4_to_f16x8(wpk4[(2 * 4 + ct) * 64 + lane]), zero,
                    0, 0, 0);
                acc = __builtin_amdgcn_mfma_f32_16x16x32_f16(
                    A[1][1], u4_to_f16x8(wpk4[(3 * 4 + ct) * 64 + lane]), acc,
                    0, 0, 0);
                acc = __builtin_amdgcn_mfma_f32_16x16x32_f16(
                    A[2][0], u4_to_f16x8(wpk4[(4 * 4 + ct) * 64 + lane]), acc,
                    0, 0, 0);
                acc = __builtin_amdgcn_mfma_f32_16x16x32_f16(
                    A[2][1], u4_to_f16x8(wpk4[(5 * 4 + ct) * 64 + lane]), acc,
                    0, 0, 0);
#pragma unroll
                for (int r = 0; r < 4; r++) res[ct][r] += w1 * elu_f(acc[r]);
                acc = __builtin_amdgcn_mfma_f32_16x16x32_f16(
                    A[3][0], u4_to_f16x8(wpk4[(6 * 4 + ct) * 64 + lane]), zero,
                    0, 0, 0);
                acc = __builtin_amdgcn_mfma_f32_16x16x32_f16(
                    A[3][1], u4_to_f16x8(wpk4[(7 * 4 + ct) * 64 + lane]), acc,
                    0, 0, 0);
#pragma unroll
                for (int r = 0; r < 4; r++) res[ct][r] += w2 * elu_f(acc[r]);
                acc = __builtin_amdgcn_mfma_f32_16x16x32_f16(
                    A[4][0], u4_to_f16x8(wpk4[(8 * 4 + ct) * 64 + lane]), zero,
                    0, 0, 0);
                acc = __builtin_amdgcn_mfma_f32_16x16x32_f16(
                    A[4][1], u4_to_f16x8(wpk4[(9 * 4 + ct) * 64 + lane]), acc,
                    0, 0, 0);
#pragma unroll
                for (int r = 0; r < 4; r++) res[ct][r] += w3 * elu_f(acc[r]);
            }

            // C/D layout: col(feature)=lane&15, row(node)=kg*4+r
#pragma unroll
            for (int ct = 0; ct < 4; ct++)
#pragma unroll
                for (int r = 0; r < 4; r++) {
                    int node = t * 16 + kg * 4 + r;
                    out[(size_t)node * 64 + ct * 16 + nl] = res[ct][r];
                }
        }
        __syncthreads();
    }
}

extern "C" void kernel_launch(void* const* d_in, const int* in_sizes, int n_in,
                              void* d_out, int out_size, void* d_ws,
                              size_t ws_size, hipStream_t stream) {
    const float* x = (const float*)d_in[0];
    const float* wts = (const float*)d_in[1];
    const int* ei = (const int*)d_in[2];  // int32 (jax x64 disabled)
    const int* src = ei;
    const int* dst = ei + N_EDGES;
    const float* Wgcn = (const float*)d_in[3];
    const float* Wss = (const float*)d_in[4];
    const float* Wsn = (const float*)d_in[5];
    const float* Wgin = (const float*)d_in[6];
    const float* Wgat = (const float*)d_in[7];
    const float* a_src = (const float*)d_in[8];
    const float* a_dst = (const float*)d_in[9];
    float* out = (float*)d_out;

    const size_t N = N_NODES;
    char* p = (char*)d_ws;
    unsigned int* xh = (unsigned int*)p;  // [(N+1)*32]
    p += (N + 1) * 32 * sizeof(unsigned int);
    int* srtF = (int*)p;  // [N*CAP]
    p += N * CAP * sizeof(int);
    int* esrtP = (int*)p;  // [E] packed (src | rem<<17)
    p += (size_t)N_EDGES * sizeof(int);
    int* blockHist = (int*)p;  // [NB*NB]
    p += NB * NB * sizeof(int);
    int* binBase = (int*)p;  // [NB+1]
    p += (NB + 1) * sizeof(int);
    float2* scal2 = (float2*)p;  // [N+1] {alpha_s, dinv}
    p += (N + 1) * sizeof(float2);
    float* alpha_d = (float*)p;  // [N]
    p += N * sizeof(float);
    int* ncnt = (int*)p;  // [N]
    p += N * sizeof(int);
    unsigned int* wpk = (unsigned int*)p;  // [10240] packed B-frags
    p += 10240 * sizeof(unsigned int);

    const int E4 = N_EDGES / 4;

    k_hist<<<NB + PACKB, 256, 0, stream>>>(
        (const int4*)dst, blockHist, (const float4*)x, Wgcn, Wss, Wsn, Wgin,
        Wgat, a_src, a_dst, xh, scal2, alpha_d, wpk, E4, N_NODES);
    k_part<<<NB, 1024, 0, stream>>>((const int4*)src, (const int4*)dst,
                                    blockHist, esrtP, binBase, E4, N_EDGES);
    k_fill2<<<NB, 1024, 0, stream>>>(esrtP, binBase, srtF, ncnt, scal2,
                                     N_NODES);
    k_aggfin<<<1024, 512, 0, stream>>>(xh, scal2, alpha_d, ncnt, srtF,
                                       (const uint4*)xh, (const uint4*)wpk,
                                       wts, out, N_NODES / 16);
}

// Round 19
// 127.619 us; speedup vs baseline: 1.7312x; 1.7312x over previous
//
#include <hip/hip_runtime.h>
#include <hip/hip_fp16.h>

#define N_NODES 100000
#define N_EDGES 1600000
#define DIM 64
#define NEG_SLOPE 0.2f
#define CAP 64
#define NB 256          // partition bins == chunks
#define BW 391          // bin width: 256*391 = 100096 >= N
#define PACKB 512

__device__ __forceinline__ float elu_f(float v) {
    return v > 0.f ? v : (__expf(v) - 1.f);
}
__device__ __forceinline__ float leaky_f(float v) {
    return v > 0.f ? v : NEG_SLOPE * v;
}
__device__ __forceinline__ int pad4(int v) { return (v + 3) & ~3; }

__device__ __forceinline__ unsigned int pkh2(float a, float b) {
    __half2 h = __floats2half2_rn(a, b);
    return *(unsigned int*)&h;
}
__device__ __forceinline__ float2 uph2(unsigned int u) {
    __half2 h = *(__half2*)&u;
    return __half22float2(h);
}

typedef _Float16 f16x8 __attribute__((ext_vector_type(8)));
typedef float f32x4 __attribute__((ext_vector_type(4)));

__device__ __forceinline__ f16x8 u4_to_f16x8(uint4 u) {
    f16x8 r;
    __builtin_memcpy(&r, &u, 16);
    return r;
}

__device__ __forceinline__ int chunk_beg4(int c, int E4) {
    return (int)(((long long)c * E4) / NB);
}

// ---- K1: hist (blocks 0..NB-1): per-chunk 256-bin LDS histogram of dst
//      (int4). Pack (blocks NB..): x->half2 (float4, 16 lanes/node) + alphas
//      + wpk + dummy node. ----
__global__ void __launch_bounds__(256) k_hist(
    const int4* __restrict__ dst4, int* __restrict__ blockHist,
    const float4* __restrict__ xf4, const float* __restrict__ Wgcn,
    const float* __restrict__ Wss, const float* __restrict__ Wsn,
    const float* __restrict__ Wgin, const float* __restrict__ Wgat,
    const float* __restrict__ a_src, const float* __restrict__ a_dst,
    unsigned int* __restrict__ xh, float2* __restrict__ scal2,
    float* __restrict__ alpha_d, unsigned int* __restrict__ wpk, int E4,
    int N) {
    if ((int)blockIdx.x < NB) {
        __shared__ int hist[NB];
        for (int j = threadIdx.x; j < NB; j += 256) hist[j] = 0;
        __syncthreads();
        const int beg = chunk_beg4(blockIdx.x, E4);
        const int end = chunk_beg4(blockIdx.x + 1, E4);
        for (int i = beg + threadIdx.x; i < end; i += 256) {
            int4 d = dst4[i];
            atomicAdd(&hist[d.x / BW], 1);
            atomicAdd(&hist[d.y / BW], 1);
            atomicAdd(&hist[d.z / BW], 1);
            atomicAdd(&hist[d.w / BW], 1);
        }
        __syncthreads();
        for (int j = threadIdx.x; j < NB; j += 256)
            blockHist[j * NB + blockIdx.x] = hist[j];  // bin-major
        return;
    }

    const int pbid = blockIdx.x - NB;
    __shared__ float svs[64], svd[64];
    if (threadIdx.x < 64) {
        int t = threadIdx.x;
        float vs = 0.f, vd = 0.f;
        for (int j = 0; j < 64; j++) {
            float w = Wgat[t * 64 + j];
            vs = fmaf(w, a_src[j], vs);
            vd = fmaf(w, a_dst[j], vd);
        }
        svs[t] = vs;
        svd[t] = vd;
    }
    __syncthreads();

    if (pbid == 0) {
        if (threadIdx.x < 32) xh[(size_t)N * 32 + threadIdx.x] = 0u;
        if (threadIdx.x == 32) scal2[N] = make_float2(-1e30f, 0.f);
    }
    if (pbid == 1) {
        // wpk[idx], idx = (((m*2+ks)*4+ct)*64+lane)*4+jp  (MFMA B-frag layout)
        for (int idx = threadIdx.x; idx < 10240; idx += 256) {
            int jp = idx & 3;
            int lane = (idx >> 2) & 63;
            int ct = (idx >> 8) & 3;
            int mks = idx >> 10;
            int m = mks >> 1, ks = mks & 1;
            int k = ks * 32 + ((lane >> 4) << 3) + jp * 2;
            int col = ct * 16 + (lane & 15);
            const float* Wm = (m == 0)   ? Wgcn
                              : (m == 1) ? Wss
                              : (m == 2) ? Wsn
                              : (m == 3) ? Wgin
                                         : Wgat;
            wpk[idx] = pkh2(Wm[k * 64 + col], Wm[(k + 1) * 64 + col]);
        }
    }

    const int lane = threadIdx.x & 63;
    const int wv = threadIdx.x >> 6;
    const int c16 = lane & 15;
    const int g4 = lane >> 4;  // node-in-quad
    const int nquads = N / 4;

    for (int q = pbid * 4 + wv; q < nquads; q += PACKB * 4) {
        int n = q * 4 + g4;
        float4 x4 = xf4[(size_t)n * 16 + c16];
        uint2 pk = make_uint2(pkh2(x4.x, x4.y), pkh2(x4.z, x4.w));
        ((uint2*)xh)[(size_t)n * 16 + c16] = pk;
        float ps = x4.x * svs[4 * c16] + x4.y * svs[4 * c16 + 1] +
                   x4.z * svs[4 * c16 + 2] + x4.w * svs[4 * c16 + 3];
        float pd = x4.x * svd[4 * c16] + x4.y * svd[4 * c16 + 1] +
                   x4.z * svd[4 * c16 + 2] + x4.w * svd[4 * c16 + 3];
#pragma unroll
        for (int m = 8; m; m >>= 1) {
            ps += __shfl_xor(ps, m, 64);
            pd += __shfl_xor(pd, m, 64);
        }
        if (c16 == 0) {
            scal2[n].x = ps;
            alpha_d[n] = pd;
        }
    }
}

// ---- K2: partition with self-computed offsets; packed (src | rem<<17).
//      1024 threads: 16 waves/CU to hide scattered-store latency. ----
__global__ void __launch_bounds__(1024) k_part(const int4* __restrict__ src4,
                                               const int4* __restrict__ dst4,
                                               const int* __restrict__ bh,
                                               int* __restrict__ esrtP,
                                               int* __restrict__ binBase,
                                               int E4, int E) {
    __shared__ int off[NB];
    __shared__ int tmp[NB];
    const int t = threadIdx.x;
    const int chunk = blockIdx.x;

    // per-bin total + prefix up to my chunk (thread t<NB owns bin t)
    int myTot = 0, myPre = 0;
    if (t < NB) {
        const int* row = bh + t * NB;
        for (int i = 0; i < NB; i++) {
            int v = row[i];
            myTot += v;
            if (i < chunk) myPre += v;
        }
        tmp[t] = myTot;
    }
    __syncthreads();
    for (int d = 1; d < NB; d <<= 1) {
        int v = (t >= d && t < NB) ? tmp[t - d] : 0;
        __syncthreads();
        if (t < NB) tmp[t] += v;
        __syncthreads();
    }
    if (t < NB) {
        int binExcl = tmp[t] - myTot;
        off[t] = binExcl + myPre;
        if (chunk == 0) {
            binBase[t] = binExcl;
            if (t == 0) binBase[NB] = E;
        }
    }
    __syncthreads();

    const int beg = chunk_beg4(chunk, E4);
    const int end = chunk_beg4(chunk + 1, E4);
    for (int i = beg + t; i < end; i += 1024) {
        int4 s = src4[i];
        int4 d = dst4[i];
        int b0 = d.x / BW, b1 = d.y / BW, b2 = d.z / BW, b3 = d.w / BW;
        int p0 = atomicAdd(&off[b0], 1);
        esrtP[p0] = s.x | ((d.x - b0 * BW) << 17);
        int p1 = atomicAdd(&off[b1], 1);
        esrtP[p1] = s.y | ((d.y - b1 * BW) << 17);
        int p2 = atomicAdd(&off[b2], 1);
        esrtP[p2] = s.z | ((d.z - b2 * BW) << 17);
        int p3 = atomicAdd(&off[b3], 1);
        esrtP[p3] = s.w | ((d.w - b3 * BW) << 17);
    }
}

// ---- K3: per-bin fill (1024 threads): LDS slot counters -> srtF + ncnt + dinv ----
__global__ void __launch_bounds__(1024) k_fill2(const int* __restrict__ esrtP,
                                                const int* __restrict__ binBase,
                                                int* __restrict__ srtF,
                                                int* __restrict__ ncnt,
                                                float2* __restrict__ scal2,
                                                int N) {
    __shared__ int lcnt[BW];
    const int j = blockIdx.x;
    const int lo = j * BW;
    for (int k = threadIdx.x; k < BW; k += 1024) lcnt[k] = 0;
    __syncthreads();
    const int beg = binBase[j];
    const int end = binBase[j + 1];
    for (int i = beg + threadIdx.x; i < end; i += 1024) {
        int v = esrtP[i];
        int s = v & 131071;
        int rem = v >> 17;
        int sl = atomicAdd(&lcnt[rem], 1);
        if (sl < CAP) srtF[(size_t)(lo + rem) * CAP + sl] = s;
    }
    __syncthreads();
    for (int k = threadIdx.x; k < BW; k += 1024) {
        int n = lo + k;
        if (n < N) {
            int cv = lcnt[k];
            ncnt[n] = cv;
            scal2[n].y = rsqrtf((float)(cv + 1));
        }
    }
}

// ---- K4: aggregation. wave per node; 16-edge iter = 8 loads in flight ----
__global__ void __launch_bounds__(512) k_agg(
    const unsigned int* __restrict__ xh, const float2* __restrict__ scal2,
    const float* __restrict__ alpha_d, const int* __restrict__ ncnt,
    const int* __restrict__ srtF, unsigned int* __restrict__ aggN,
    unsigned int* __restrict__ aggG, unsigned int* __restrict__ aggA,
    float* __restrict__ aggD, int N) {
    __shared__ int sSl[8][64];
    __shared__ float2 sED[8][64];

    const int lane = threadIdx.x & 63;
    const int w = threadIdx.x >> 6;
    const int c = lane & 31;
    const int hf = lane >> 5;
    const int wid = blockIdx.x * 8 + w;
    const int nw = gridDim.x * 8;

    for (int n = wid; n < N; n += nw) {
        const int deg = min(ncnt[n], CAP);
        const float ad = alpha_d[n];

        int sl = (lane < deg) ? srtF[(size_t)n * CAP + lane] : N_NODES;
        float2 sc = scal2[sl];
        float ee = __expf(leaky_f(sc.x + ad));  // dummy: exp(-inf)=0
        float den = ee;
        sSl[w][lane] = sl;
        sED[w][lane] = make_float2(ee, sc.y);

        float2 an = {0.f, 0.f}, ag = {0.f, 0.f}, aa = {0.f, 0.f};
        const int jmax = pad4(deg);
        int j = 0;
        // 16 edges/iter: 8 independent gathers in flight per lane
        for (; j + 16 <= jmax; j += 16) {
            int ss[8];
            float2 ed[8];
            unsigned int uu[8];
#pragma unroll
            for (int k = 0; k < 8; k++) {
                int b = j + hf + 2 * k;
                ss[k] = sSl[w][b];
                ed[k] = sED[w][b];
            }
#pragma unroll
            for (int k = 0; k < 8; k++) uu[k] = xh[(size_t)ss[k] * 32 + c];
#pragma unroll
            for (int k = 0; k < 8; k++) {
                float2 f = uph2(uu[k]);
                an.x += f.x;
                an.y += f.y;
                ag.x = fmaf(ed[k].y, f.x, ag.x);
                ag.y = fmaf(ed[k].y, f.y, ag.y);
                aa.x = fmaf(ed[k].x, f.x, aa.x);
                aa.y = fmaf(ed[k].x, f.y, aa.y);
            }
        }
        if (j + 8 <= jmax) {  // 8-edge tail
            int b0 = j + hf, b1 = b0 + 2, b2 = b0 + 4, b3 = b0 + 6;
            int s0 = sSl[w][b0], s1 = sSl[w][b1];
            int s2 = sSl[w][b2], s3 = sSl[w][b3];
            float2 e0 = sED[w][b0], e1 = sED[w][b1];
            float2 e2 = sED[w][b2], e3 = sED[w][b3];
            unsigned int u0 = xh[(size_t)s0 * 32 + c];
            unsigned int u1 = xh[(size_t)s1 * 32 + c];
            unsigned int u2 = xh[(size_t)s2 * 32 + c];
            unsigned int u3 = xh[(size_t)s3 * 32 + c];
            float2 f0 = uph2(u0), f1 = uph2(u1);
            float2 f2 = uph2(u2), f3 = uph2(u3);
            an.x += (f0.x + f1.x) + (f2.x + f3.x);
            an.y += (f0.y + f1.y) + (f2.y + f3.y);
            ag.x = fmaf(e0.y, f0.x,
                        fmaf(e1.y, f1.x, fmaf(e2.y, f2.x,
                                              fmaf(e3.y, f3.x, ag.x))));
            ag.y = fmaf(e0.y, f0.y,
                        fmaf(e1.y, f1.y, fmaf(e2.y, f2.y,
                                              fmaf(e3.y, f3.y, ag.y))));
            aa.x = fmaf(e0.x, f0.x,
                        fmaf(e1.x, f1.x, fmaf(e2.x, f2.x,
                                              fmaf(e3.x, f3.x, aa.x))));
            aa.y = fmaf(e0.x, f0.y,
                        fmaf(e1.x, f1.y, fmaf(e2.x, f2.y,
                                              fmaf(e3.x, f3.y, aa.y))));
            j += 8;
        }
        if (j < jmax) {  // 4-edge tail
            int b0 = j + hf, b1 = b0 + 2;
            int s0 = sSl[w][b0], s1 = sSl[w][b1];
            float2 e0 = sED[w][b0], e1 = sED[w][b1];
            unsigned int u0 = xh[(size_t)s0 * 32 + c];
            unsigned int u1 = xh[(size_t)s1 * 32 + c];
            float2 f0 = uph2(u0), f1 = uph2(u1);
            an.x += f0.x + f1.x;
            an.y += f0.y + f1.y;
            ag.x = fmaf(e0.y, f0.x, fmaf(e1.y, f1.x, ag.x));
            ag.y = fmaf(e0.y, f0.y, fmaf(e1.y, f1.y, ag.y));
            aa.x = fmaf(e0.x, f0.x, fmaf(e1.x, f1.x, aa.x));
            aa.y = fmaf(e0.x, f0.y, fmaf(e1.x, f1.y, aa.y));
        }

        an.x += __shfl_xor(an.x, 32, 64);
        an.y += __shfl_xor(an.y, 32, 64);
        ag.x += __shfl_xor(ag.x, 32, 64);
        ag.y += __shfl_xor(ag.y, 32, 64);
        aa.x += __shfl_xor(aa.x, 32, 64);
        aa.y += __shfl_xor(aa.y, 32, 64);
#pragma unroll
        for (int m = 32; m; m >>= 1) den += __shfl_xor(den, m, 64);

        if (lane < 32) {
            size_t o = (size_t)n * 32 + c;
            aggN[o] = pkh2(an.x, an.y);
            aggG[o] = pkh2(ag.x, ag.y);
            aggA[o] = pkh2(aa.x, aa.y);
        }
        if (lane == 0) aggD[n] = den;
    }
}

// ---- K5: MFMA finalize. x fragments read from fp16 xh (no f32 x read) ----
__global__ void __launch_bounds__(256) k_finalize(
    const uint4* __restrict__ xh4, const uint4* __restrict__ aggN4,
    const uint4* __restrict__ aggG4, const uint4* __restrict__ aggA4,
    const float* __restrict__ aggD, const float2* __restrict__ scal2,
    const float* __restrict__ alpha_d, const int* __restrict__ ncnt,
    const uint4* __restrict__ wpk4, const float* __restrict__ wts,
    float* __restrict__ out, int NT) {
    __shared__ uint4 sB[2560];  // 40KB: B-frags [(m*2+ks)*4+ct][lane]
    for (int i = threadIdx.x; i < 2560; i += 256) sB[i] = wpk4[i];
    __syncthreads();

    const int lane = threadIdx.x & 63;
    const int wv = threadIdx.x >> 6;
    const int kg = lane >> 4;  // k-group 0..3
    const int nl = lane & 15;  // A-row (node in tile)
    const float w0 = wts[0], w1 = wts[1], w2 = wts[2], w3 = wts[3];

    for (int t = blockIdx.x * 4 + wv; t < NT; t += gridDim.x * 4) {
        const int n = t * 16 + nl;
        const int cnt = ncnt[n];
        const float ad = alpha_d[n];
        const float dv = rsqrtf((float)(cnt + 1));
        const float as = scal2[n].x;
        const float den = aggD[n];
        const float ee_s = __expf(leaky_f(as + ad));
        const float dent = den + ee_s;
        const float icnt = 1.f / fmaxf((float)cnt, 1.f);
        const float dv2 = dv * dv;

        // build A-fragments in registers: lane covers k = ks*32 + kg*8 + 0..7
        unsigned int fa[5][2][4];
#pragma unroll
        for (int ks = 0; ks < 2; ks++) {
            uint4 uX = xh4[(size_t)n * 8 + ks * 4 + kg];
            uint4 uN = aggN4[(size_t)n * 8 + ks * 4 + kg];
            uint4 uG = aggG4[(size_t)n * 8 + ks * 4 + kg];
            uint4 uA = aggA4[(size_t)n * 8 + ks * 4 + kg];
            unsigned int ux[4] = {uX.x, uX.y, uX.z, uX.w};
            unsigned int un[4] = {uN.x, uN.y, uN.z, uN.w};
            unsigned int ug[4] = {uG.x, uG.y, uG.z, uG.w};
            unsigned int ua[4] = {uA.x, uA.y, uA.z, uA.w};
#pragma unroll
            for (int c4 = 0; c4 < 4; c4++) {
                float2 xf = uph2(ux[c4]);
                float xx = xf.x, xy = xf.y;
                float2 nn = uph2(un[c4]);
                float2 gg = uph2(ug[c4]);
                float2 av = uph2(ua[c4]);
                fa[0][ks][c4] = pkh2(fmaf(dv, gg.x, dv2 * xx),
                                     fmaf(dv, gg.y, dv2 * xy));  // GCN
                fa[1][ks][c4] = ux[c4];                          // x (Wss)
                fa[2][ks][c4] = pkh2(nn.x * icnt, nn.y * icnt);  // nmean
                fa[3][ks][c4] = pkh2(xx + nn.x, xy + nn.y);      // GIN
                fa[4][ks][c4] = pkh2(fmaf(ee_s, xx, av.x) / dent,
                                     fmaf(ee_s, xy, av.y) / dent);  // GAT
            }
        }
        f16x8 A[5][2];
#pragma unroll
        for (int m = 0; m < 5; m++)
#pragma unroll
            for (int ks = 0; ks < 2; ks++) {
                uint4 u = make_uint4(fa[m][ks][0], fa[m][ks][1], fa[m][ks][2],
                                     fa[m][ks][3]);
                A[m][ks] = u4_to_f16x8(u);
            }

        float res[4][4];
        const f32x4 zero = {0.f, 0.f, 0.f, 0.f};
#pragma unroll
        for (int ct = 0; ct < 4; ct++) {
            // GCN
            f32x4 acc = __builtin_amdgcn_mfma_f32_16x16x32_f16(
                A[0][0], u4_to_f16x8(sB[(0 * 4 + ct) * 64 + lane]), zero, 0, 0,
                0);
            acc = __builtin_amdgcn_mfma_f32_16x16x32_f16(
                A[0][1], u4_to_f16x8(sB[(1 * 4 + ct) * 64 + lane]), acc, 0, 0,
                0);
#pragma unroll
            for (int r = 0; r < 4; r++) res[ct][r] = w0 * elu_f(acc[r]);
            // SAGE = x@Wss + nmean@Wsn (chained C)
            acc = __builtin_amdgcn_mfma_f32_16x16x32_f16(
                A[1][0], u4_to_f16x8(sB[(2 * 4 + ct) * 64 + lane]), zero, 0, 0,
                0);
            acc = __builtin_amdgcn_mfma_f32_16x16x32_f16(
                A[1][1], u4_to_f16x8(sB[(3 * 4 + ct) * 64 + lane]), acc, 0, 0,
                0);
            acc = __builtin_amdgcn_mfma_f32_16x16x32_f16(
                A[2][0], u4_to_f16x8(sB[(4 * 4 + ct) * 64 + lane]), acc, 0, 0,
                0);
            acc = __builtin_amdgcn_mfma_f32_16x16x32_f16(
                A[2][1], u4_to_f16x8(sB[(5 * 4 + ct) * 64 + lane]), acc, 0, 0,
                0);
#pragma unroll
            for (int r = 0; r < 4; r++) res[ct][r] += w1 * elu_f(acc[r]);
            // GIN
            acc = __builtin_amdgcn_mfma_f32_16x16x32_f16(
                A[3][0], u4_to_f16x8(sB[(6 * 4 + ct) * 64 + lane]), zero, 0, 0,
                0);
            acc = __builtin_amdgcn_mfma_f32_16x16x32_f16(
                A[3][1], u4_to_f16x8(sB[(7 * 4 + ct) * 64 + lane]), acc, 0, 0,
                0);
#pragma unroll
            for (int r = 0; r < 4; r++) res[ct][r] += w2 * elu_f(acc[r]);
            // GAT
            acc = __builtin_amdgcn_mfma_f32_16x16x32_f16(
                A[4][0], u4_to_f16x8(sB[(8 * 4 + ct) * 64 + lane]), zero, 0, 0,
                0);
            acc = __builtin_amdgcn_mfma_f32_16x16x32_f16(
                A[4][1], u4_to_f16x8(sB[(9 * 4 + ct) * 64 + lane]), acc, 0, 0,
                0);
#pragma unroll
            for (int r = 0; r < 4; r++) res[ct][r] += w3 * elu_f(acc[r]);
        }

        // C/D layout: col(feature)=lane&15, row(node)=kg*4+r
#pragma unroll
        for (int ct = 0; ct < 4; ct++)
#pragma unroll
            for (int r = 0; r < 4; r++) {
                int node = t * 16 + kg * 4 + r;
                out[(size_t)node * 64 + ct * 16 + nl] = res[ct][r];
            }
    }
}

extern "C" void kernel_launch(void* const* d_in, const int* in_sizes, int n_in,
                              void* d_out, int out_size, void* d_ws,
                              size_t ws_size, hipStream_t stream) {
    const float* x = (const float*)d_in[0];
    const float* wts = (const float*)d_in[1];
    const int* ei = (const int*)d_in[2];  // int32 (jax x64 disabled)
    const int* src = ei;
    const int* dst = ei + N_EDGES;
    const float* Wgcn = (const float*)d_in[3];
    const float* Wss = (const float*)d_in[4];
    const float* Wsn = (const float*)d_in[5];
    const float* Wgin = (const float*)d_in[6];
    const float* Wgat = (const float*)d_in[7];
    const float* a_src = (const float*)d_in[8];
    const float* a_dst = (const float*)d_in[9];
    float* out = (float*)d_out;

    const size_t N = N_NODES;
    char* p = (char*)d_ws;
    unsigned int* xh = (unsigned int*)p;  // [(N+1)*32]
    p += (N + 1) * 32 * sizeof(unsigned int);
    int* srtF = (int*)p;  // [N*CAP]
    p += N * CAP * sizeof(int);
    int* esrtP = (int*)p;  // [E] packed (src | rem<<17)
    p += (size_t)N_EDGES * sizeof(int);
    int* blockHist = (int*)p;  // [NB*NB]
    p += NB * NB * sizeof(int);
    int* binBase = (int*)p;  // [NB+1]
    p += (NB + 1) * sizeof(int);
    float2* scal2 = (float2*)p;  // [N+1] {alpha_s, dinv}
    p += (N + 1) * sizeof(float2);
    float* alpha_d = (float*)p;  // [N]
    p += N * sizeof(float);
    int* ncnt = (int*)p;  // [N]
    p += N * sizeof(int);
    unsigned int* aggN = (unsigned int*)p;  // [N*32]
    p += N * 32 * sizeof(unsigned int);
    unsigned int* aggG = (unsigned int*)p;  // [N*32]
    p += N * 32 * sizeof(unsigned int);
    unsigned int* aggA = (unsigned int*)p;  // [N*32]
    p += N * 32 * sizeof(unsigned int);
    float* aggD = (float*)p;  // [N]
    p += N * sizeof(float);
    unsigned int* wpk = (unsigned int*)p;  // [10240] packed B-frags
    p += 10240 * sizeof(unsigned int);

    const int E4 = N_EDGES / 4;

    k_hist<<<NB + PACKB, 256, 0, stream>>>(
        (const int4*)dst, blockHist, (const float4*)x, Wgcn, Wss, Wsn, Wgin,
        Wgat, a_src, a_dst, xh, scal2, alpha_d, wpk, E4, N_NODES);
    k_part<<<NB, 1024, 0, stream>>>((const int4*)src, (const int4*)dst,
                                    blockHist, esrtP, binBase, E4, N_EDGES);
    k_fill2<<<NB, 1024, 0, stream>>>(esrtP, binBase, srtF, ncnt, scal2,
                                     N_NODES);
    k_agg<<<2048, 512, 0, stream>>>(xh, scal2, alpha_d, ncnt, srtF, aggN,
                                    aggG, aggA, aggD, N_NODES);
    k_finalize<<<512, 256, 0, stream>>>(
        (const uint4*)xh, (const uint4*)aggN, (const uint4*)aggG,
        (const uint4*)aggA, aggD, scal2, alpha_d, ncnt, (const uint4*)wpk, wts,
        out, N_NODES / 16);
}